// Round 1
// baseline (1329.716 us; speedup 1.0000x reference)
//
#include <hip/hip_runtime.h>

// ---------------------------------------------------------------------------
// 3-axis window attention (video-Swin style), MI355X gfx950.
// Strategy: one workgroup per window (49 or 56 tokens, padded to 64 rows),
// 512 threads = 8 waves. bf16 MFMA (16x16x32) for QKV-GEMM, QK^T, PV, proj.
// Weights pre-transposed to bf16 [out_col][k] in d_ws by a prep kernel.
// Branch 0 (xy) writes out with '='; branches 1,2 accumulate '+=' (stream-
// ordered, windows within a branch are disjoint).
// ---------------------------------------------------------------------------

typedef __attribute__((ext_vector_type(8))) short short8v;   // 8 x bf16 frag
typedef __attribute__((ext_vector_type(4))) short short4v;
typedef __attribute__((ext_vector_type(4))) float floatx4;

#define MFMA16(a, b, c) __builtin_amdgcn_mfma_f32_16x16x32_bf16((a), (b), (c), 0, 0, 0)

// XOR swizzle: permute 16B blocks within 128B, keyed by row. Conflict-free
// ds_read_b128 for row-strided fragment reads (stride 128B/256B).
#define SWZ(row, b) ((b) ^ (((row) & 7) << 4))

__device__ __forceinline__ short f2bf(float f) {  // RNE f32->bf16 bits
  unsigned u = __float_as_uint(f);
  u += 0x7fffu + ((u >> 16) & 1u);
  return (short)(u >> 16);
}

// ---- LDS layout (bytes), total 62464 <= 64KB -> 2 blocks/CU ----
#define XS_OFF 0        // [64][256]  x window bf16 (128 cols), swizzled
#define QS_OFF 16384    // [64][128]  q bf16 (32 cols used), swizzled, pre-scaled
#define KS_OFF 24576    // [64][128]  k bf16
#define VT_OFF 32768    // [32][128]  v^T bf16 (row=c, col=kv), swizzled
#define S_OFF  36864    // [64][272]  f32 scores; P(bf16,128B) aliases row start
#define OH_OFF 54272    // [64][128]  per-head attn-out bf16 (32 cols), swizzled
#define LDS_BYTES 62464

// D=8, H=56, W=56 fixed by the problem; B runtime via grid.
template<int BRANCH>
__device__ __forceinline__ int win_base(int wid) {
  if constexpr (BRANCH == 0) {            // xy: (b,d,hb,wb), tok=(ih,iw)
    int b = wid >> 9, r = wid & 511;
    int d = r >> 6, hb = (r >> 3) & 7, wb = r & 7;
    return ((b * 8 + d) * 56 + hb * 7) * 56 + wb * 7;
  } else if constexpr (BRANCH == 1) {     // ty: (b,hb,wcol), tok=(id,ih)
    int b = wid / 448, r = wid % 448;
    int hb = r / 56, wc = r % 56;
    return (b * 8 * 56 + hb * 7) * 56 + wc;
  } else {                                // tx: (b,h,wb), tok=(id,iw)
    int b = wid / 448, r = wid % 448;
    int h = r >> 3, wb = r & 7;
    return (b * 8 * 56 + h) * 56 + wb * 7;
  }
}
template<int BRANCH>
__device__ __forceinline__ int tok_off(int t) {
  int q = t / 7, rm = t - q * 7;
  if constexpr (BRANCH == 0) return q * 56 + rm;          // ih*56 + iw
  else if constexpr (BRANCH == 1) return q * 3136 + rm * 56; // id*D(HW)? id*56*56 + ih*56
  else return q * 3136 + rm;                              // id*56*56 + iw
}

__global__ void prep_weights(const float* __restrict__ q0, const float* __restrict__ q1,
                             const float* __restrict__ q2, const float* __restrict__ p0,
                             const float* __restrict__ p1, const float* __restrict__ p2,
                             short* __restrict__ ws) {
  // ws: qkvT[3][384][128] bf16 then projT[3][128][128] bf16 ([out_col][k])
  int idx = blockIdx.x * 256 + threadIdx.x;
  if (idx < 3 * 49152) {
    int b = idx / 49152, r = idx % 49152;
    int n = r >> 7, k = r & 127;
    const float* s = (b == 0) ? q0 : (b == 1) ? q1 : q2;
    ws[idx] = f2bf(s[k * 384 + n]);
  } else if (idx < 3 * 49152 + 3 * 16384) {
    int j = idx - 3 * 49152;
    int b = j / 16384, r = j % 16384;
    int n = r >> 7, k = r & 127;
    const float* s = (b == 0) ? p0 : (b == 1) ? p1 : p2;
    ws[idx] = f2bf(s[k * 128 + n]);
  }
}

template<int BRANCH, int NTOK>
__global__ __launch_bounds__(512, 4)
void wattn(const float* __restrict__ x, const short* __restrict__ wqkvT,
           const float* __restrict__ bqkv, const short* __restrict__ wprojT,
           const float* __restrict__ bproj, float* __restrict__ out) {
  __shared__ alignas(256) char smem[LDS_BYTES];
  const int tid = threadIdx.x;
  const int w = tid >> 6;            // wave 0..7
  const int l = tid & 63;
  const int l15 = l & 15;
  const int l4 = l >> 4;             // 0..3
  const int wid = blockIdx.x;
  const int base = win_base<BRANCH>(wid);
  const float SCALE = 0.17677669529663687f;  // 32^-0.5

  // ---- Phase A: stage x window into LDS as bf16 (pad rows zeroed) ----
  {
    int rg = tid >> 5;               // 16 row-groups
    int c4 = (tid & 31) << 2;        // col 0..124 step 4
    for (int t = rg; t < 64; t += 16) {
      short4v v4;
      if (t < NTOK) {
        const float4* xp =
            (const float4*)(x + (((size_t)(base + tok_off<BRANCH>(t))) << 7) + c4);
        float4 xv = *xp;
        v4.x = f2bf(xv.x); v4.y = f2bf(xv.y); v4.z = f2bf(xv.z); v4.w = f2bf(xv.w);
      } else {
        v4.x = 0; v4.y = 0; v4.z = 0; v4.w = 0;
      }
      *(short4v*)(&smem[XS_OFF + t * 256 + SWZ(t, c4 * 2)]) = v4;
    }
  }
  __syncthreads();

  // persistent proj accumulators: wave w owns out tiles (mtJ, ntbJ..ntbJ+3)
  const int mtJ = w & 3, ntbJ = (w >> 2) * 4;
  floatx4 pacc[4];
  #pragma unroll
  for (int i = 0; i < 4; ++i) pacc[i] = (floatx4){0.f, 0.f, 0.f, 0.f};

  const int mtB = w & 3, ntbB = (w >> 2) * 3;   // qkv-gemm tiles
  const int mtP = w >> 1, ctP = w & 1;          // pv tile

  #pragma unroll 1
  for (int h = 0; h < 4; ++h) {
    // ---- QKV gemm: [64 x 96] = X[64 x 128] * Wh[128 x 96] ----
    {
      floatx4 acc[3];
      #pragma unroll
      for (int i = 0; i < 3; ++i) acc[i] = (floatx4){0.f, 0.f, 0.f, 0.f};
      const int arow = mtB * 16 + l15;
      #pragma unroll
      for (int kt = 0; kt < 4; ++kt) {
        short8v af = *(const short8v*)(&smem[XS_OFF + arow * 256 + SWZ(arow, kt * 64 + l4 * 16)]);
        #pragma unroll
        for (int i = 0; i < 3; ++i) {
          int nt = ntbB + i;
          int gcol = ((nt >> 1) << 7) + (h << 5) + ((nt & 1) << 4) + l15;
          short8v bf = *(const short8v*)(wqkvT + (size_t)gcol * 128 + kt * 32 + l4 * 8);
          acc[i] = MFMA16(af, bf, acc[i]);
        }
      }
      // epilogue: +bias, scale q, scatter to Q / K / V^T LDS
      #pragma unroll
      for (int i = 0; i < 3; ++i) {
        int nt = ntbB + i;
        int part = nt >> 1;                       // 0=q,1=k,2=v (wave-uniform)
        int cc = ((nt & 1) << 4) + l15;           // 0..31 within head
        float bias = bqkv[(part << 7) + (h << 5) + cc];
        if (part == 0) {
          #pragma unroll
          for (int r = 0; r < 4; ++r) {
            int row = mtB * 16 + l4 * 4 + r;
            *(short*)(&smem[QS_OFF + row * 128 + SWZ(row, cc * 2)]) =
                f2bf((acc[i][r] + bias) * SCALE);
          }
        } else if (part == 1) {
          #pragma unroll
          for (int r = 0; r < 4; ++r) {
            int row = mtB * 16 + l4 * 4 + r;
            *(short*)(&smem[KS_OFF + row * 128 + SWZ(row, cc * 2)]) =
                f2bf(acc[i][r] + bias);
          }
        } else {
          int colbase = mtB * 16 + l4 * 4;        // 4 consecutive kv -> b64 write
          short4v pv;
          #pragma unroll
          for (int r = 0; r < 4; ++r) pv[r] = f2bf(acc[i][r] + bias);
          *(short4v*)(&smem[VT_OFF + cc * 128 + SWZ(cc, colbase * 2)]) = pv;
        }
      }
    }
    __syncthreads();

    // ---- S = Q K^T : 16 tiles of 16x16, K=32 (one mfma each) ----
    {
      #pragma unroll
      for (int s = 0; s < 2; ++s) {
        int tileid = w * 2 + s;
        int mt = tileid >> 2, nt = tileid & 3;
        int qrow = mt * 16 + l15;
        short8v aq = *(const short8v*)(&smem[QS_OFF + qrow * 128 + SWZ(qrow, l4 * 16)]);
        int krow = nt * 16 + l15;
        short8v bk = *(const short8v*)(&smem[KS_OFF + krow * 128 + SWZ(krow, l4 * 16)]);
        floatx4 s4 = (floatx4){0.f, 0.f, 0.f, 0.f};
        s4 = MFMA16(aq, bk, s4);
        #pragma unroll
        for (int r = 0; r < 4; ++r) {
          int row = mt * 16 + l4 * 4 + r;
          *(float*)(&smem[S_OFF + row * 272 + (nt * 16 + l15) * 4]) = s4[r];
        }
      }
    }
    __syncthreads();

    // ---- wave-parallel softmax: one row per wave iter, 64-lane reduce ----
    for (int r = w; r < NTOK; r += 8) {
      float sv = (l < NTOK) ? *(const float*)(&smem[S_OFF + r * 272 + l * 4]) : -1e30f;
      float m = sv;
      #pragma unroll
      for (int off = 32; off > 0; off >>= 1) m = fmaxf(m, __shfl_xor(m, off, 64));
      float p = __expf(sv - m);
      if (l >= NTOK) p = 0.f;
      float ssum = p;
      #pragma unroll
      for (int off = 32; off > 0; off >>= 1) ssum += __shfl_xor(ssum, off, 64);
      float pn = p * __frcp_rn(ssum) ;
      // P (bf16, 64 cols=128B) aliases S row start; S row fully consumed above.
      *(short*)(&smem[S_OFF + r * 272 + l * 2]) = f2bf(pn);
    }
    __syncthreads();

    // ---- O_h = P V : [64 x 32], K=64 (2 mfma) ----
    {
      floatx4 vacc = (floatx4){0.f, 0.f, 0.f, 0.f};
      const int prow = mtP * 16 + l15;
      const int vrow = ctP * 16 + l15;
      #pragma unroll
      for (int kt = 0; kt < 2; ++kt) {
        // P rows have 272B stride -> banks rotate naturally, no XOR swizzle
        short8v ap = *(const short8v*)(&smem[S_OFF + prow * 272 + kt * 64 + l4 * 16]);
        short8v bv = *(const short8v*)(&smem[VT_OFF + vrow * 128 + SWZ(vrow, kt * 64 + l4 * 16)]);
        vacc = MFMA16(ap, bv, vacc);
      }
      #pragma unroll
      for (int r = 0; r < 4; ++r) {
        int row = mtP * 16 + l4 * 4 + r;
        int c = ctP * 16 + l15;
        *(short*)(&smem[OH_OFF + row * 128 + SWZ(row, c * 2)]) = f2bf(vacc[r]);
      }
    }
    __syncthreads();

    // ---- proj partial: pacc += O_h[64x32] * Wp[h*32..+32, 128] ----
    {
      int orow = mtJ * 16 + l15;
      short8v ao = *(const short8v*)(&smem[OH_OFF + orow * 128 + SWZ(orow, l4 * 16)]);
      #pragma unroll
      for (int i = 0; i < 4; ++i) {
        int col = (ntbJ + i) * 16 + l15;
        short8v bp = *(const short8v*)(wprojT + (size_t)col * 128 + (h << 5) + l4 * 8);
        pacc[i] = MFMA16(ao, bp, pacc[i]);
      }
    }
    __syncthreads();
  }

  // ---- final epilogue: +proj bias, write/accumulate global out ----
  #pragma unroll
  for (int i = 0; i < 4; ++i) {
    int col = (ntbJ + i) * 16 + l15;
    float pb = bproj[col];
    #pragma unroll
    for (int r = 0; r < 4; ++r) {
      int row = mtJ * 16 + l4 * 4 + r;
      if (row < NTOK) {
        size_t gi = (((size_t)(base + tok_off<BRANCH>(row))) << 7) + col;
        if constexpr (BRANCH == 0) out[gi] = pacc[i][r] + pb;
        else out[gi] += pacc[i][r] + pb;
      }
    }
  }
}

extern "C" void kernel_launch(void* const* d_in, const int* in_sizes, int n_in,
                              void* d_out, int out_size, void* d_ws, size_t ws_size,
                              hipStream_t stream) {
  const float* x         = (const float*)d_in[0];
  const float* qkv_w     = (const float*)d_in[1];
  const float* qkv_b     = (const float*)d_in[2];
  const float* qkv_th_w  = (const float*)d_in[3];
  const float* qkv_th_b  = (const float*)d_in[4];
  const float* qkv_tw_w  = (const float*)d_in[5];
  const float* qkv_tw_b  = (const float*)d_in[6];
  const float* proj_w    = (const float*)d_in[7];
  const float* proj_b    = (const float*)d_in[8];
  const float* proj_th_w = (const float*)d_in[9];
  const float* proj_th_b = (const float*)d_in[10];
  const float* proj_tw_w = (const float*)d_in[11];
  const float* proj_tw_b = (const float*)d_in[12];
  float* out = (float*)d_out;

  const int B = in_sizes[0] / (8 * 56 * 56 * 128);
  short* wsT = (short*)d_ws;

  // bf16-transpose all 6 weight matrices into workspace (~384KB)
  prep_weights<<<768, 256, 0, stream>>>(qkv_w, qkv_th_w, qkv_tw_w,
                                        proj_w, proj_th_w, proj_tw_w, wsT);

  const short* qT0 = wsT;
  const short* qT1 = wsT + 49152;
  const short* qT2 = wsT + 2 * 49152;
  const short* pT0 = wsT + 3 * 49152;
  const short* pT1 = pT0 + 16384;
  const short* pT2 = pT0 + 2 * 16384;

  // xy writes '=', then ty/tx accumulate (stream-ordered)
  wattn<0, 49><<<B * 512, 512, 0, stream>>>(x, qT0, qkv_b,    pT0, proj_b,    out);
  wattn<1, 56><<<B * 448, 512, 0, stream>>>(x, qT1, qkv_th_b, pT1, proj_th_b, out);
  wattn<2, 56><<<B * 448, 512, 0, stream>>>(x, qT2, qkv_tw_b, pT2, proj_tw_b, out);
}

// Round 4
// 985.736 us; speedup vs baseline: 1.3490x; 1.3490x over previous
//
#include <hip/hip_runtime.h>

// ---------------------------------------------------------------------------
// 3-axis window attention, MI355X gfx950.  Round 2: all-heads single pass.
// One workgroup per window (49/56 tokens padded to 64), 512 threads = 8 waves.
// 6 barrier-phases total (was 21): stage | QKV | VT-scatter+S(+in-reg softmax)
// | P-scatter | PV | O-scatter | proj.  S never touches LDS.  LDS regions
// aliased: RA = XS -> VT -> O,  RB = Q -> P(h0,h1),  RC = K -> P(h2,h3).
// 48 KB LDS -> 3 blocks/CU; launch_bounds(512,6) caps VGPR at 84.
// ---------------------------------------------------------------------------

typedef __attribute__((ext_vector_type(8))) short short8v;   // 8 x bf16 frag
typedef __attribute__((ext_vector_type(4))) short short4v;
typedef __attribute__((ext_vector_type(4))) float floatx4;

#define MFMA16(a, b, c) __builtin_amdgcn_mfma_f32_16x16x32_bf16((a), (b), (c), 0, 0, 0)

// XOR swizzles: permute 16B slots, keyed by row. SWZ8 for 128B-stride rows
// (3 key bits), SWZ16 for 256B-stride rows (4 key bits -> 16 distinct slots).
#define SWZ8(row, b)  ((b) ^ (((row) & 7) << 4))
#define SWZ16(row, b) ((b) ^ (((row) & 15) << 4))

__device__ __forceinline__ short f2bf(float f) {  // RNE f32->bf16 bits
  unsigned u = __float_as_uint(f);
  u += 0x7fffu + ((u >> 16) & 1u);
  return (short)(u >> 16);
}

// ---- LDS regions (bytes), total 48 KB ----
#define RA 0        // [64][256B] XS  ->  [128][128B] VT  ->  [64][256B] O
#define RB 16384    // [64][256B] Q   ->  P[h0],P[h1]  ([64][128B] each)
#define RC 32768    // [64][256B] K   ->  P[h2],P[h3]
#define LDS_BYTES 49152

// D=8, H=56, W=56 fixed by the problem; B runtime via grid.
template<int BRANCH>
__device__ __forceinline__ int win_base(int wid) {
  if constexpr (BRANCH == 0) {            // xy: (b,d,hb,wb), tok=(ih,iw)
    int b = wid >> 9, r = wid & 511;
    int d = r >> 6, hb = (r >> 3) & 7, wb = r & 7;
    return ((b * 8 + d) * 56 + hb * 7) * 56 + wb * 7;
  } else if constexpr (BRANCH == 1) {     // ty: (b,hb,wcol), tok=(id,ih)
    int b = wid / 448, r = wid % 448;
    int hb = r / 56, wc = r % 56;
    return (b * 8 * 56 + hb * 7) * 56 + wc;
  } else {                                // tx: (b,h,wb), tok=(id,iw)
    int b = wid / 448, r = wid % 448;
    int h = r >> 3, wb = r & 7;
    return (b * 8 * 56 + h) * 56 + wb * 7;
  }
}
template<int BRANCH>
__device__ __forceinline__ int tok_off(int t) {
  int q = t / 7, rm = t - q * 7;
  if constexpr (BRANCH == 0) return q * 56 + rm;             // ih*56 + iw
  else if constexpr (BRANCH == 1) return q * 3136 + rm * 56; // id*HW + ih*56
  else return q * 3136 + rm;                                 // id*HW + iw
}

__global__ void prep_weights(const float* __restrict__ q0, const float* __restrict__ q1,
                             const float* __restrict__ q2, const float* __restrict__ p0,
                             const float* __restrict__ p1, const float* __restrict__ p2,
                             short* __restrict__ ws) {
  // ws: qkvT[3][384][128] bf16 then projT[3][128][128] bf16 ([out_col][k])
  int idx = blockIdx.x * 256 + threadIdx.x;
  if (idx < 3 * 49152) {
    int b = idx / 49152, r = idx % 49152;
    int n = r >> 7, k = r & 127;
    const float* s = (b == 0) ? q0 : (b == 1) ? q1 : q2;
    ws[idx] = f2bf(s[k * 384 + n]);
  } else if (idx < 3 * 49152 + 3 * 16384) {
    int j = idx - 3 * 49152;
    int b = j / 16384, r = j % 16384;
    int n = r >> 7, k = r & 127;
    const float* s = (b == 0) ? p0 : (b == 1) ? p1 : p2;
    ws[idx] = f2bf(s[k * 128 + n]);
  }
}

template<int BRANCH, int NTOK>
__global__ __launch_bounds__(512, 6)
void wattn(const float* __restrict__ x, const short* __restrict__ wqkvT,
           const float* __restrict__ bqkv, const short* __restrict__ wprojT,
           const float* __restrict__ bproj, float* __restrict__ out) {
  __shared__ alignas(256) char smem[LDS_BYTES];
  const int tid = threadIdx.x;
  const int w = tid >> 6;            // wave 0..7
  const int l = tid & 63;
  const int l15 = l & 15;
  const int l4 = l >> 4;             // 0..3
  const int base = win_base<BRANCH>(blockIdx.x);
  const float SCALE = 0.17677669529663687f;  // 32^-0.5
  const floatx4 ZERO4 = {0.f, 0.f, 0.f, 0.f};

  // ---- Phase 1: stage x window -> XS (RA), bf16, pad rows zeroed ----
  {
    int rg = tid >> 5;               // 2 rows per wave-instr
    int c4 = (tid & 31) << 2;        // col 0..124 step 4
    #pragma unroll
    for (int it = 0; it < 4; ++it) {
      int t = rg + it * 16;
      short4v v4;
      if (t < NTOK) {
        float4 xv = *(const float4*)(x + (((size_t)(base + tok_off<BRANCH>(t))) << 7) + c4);
        v4.x = f2bf(xv.x); v4.y = f2bf(xv.y); v4.z = f2bf(xv.z); v4.w = f2bf(xv.w);
      } else {
        v4.x = 0; v4.y = 0; v4.z = 0; v4.w = 0;
      }
      *(short4v*)(&smem[RA + t * 256 + SWZ16(t, c4 * 2)]) = v4;
    }
  }
  __syncthreads();   // ---- bar 1 ----

  const int mt = w & 3, ng = w >> 2;       // wave's m-tile / n-half
  const int arow = mt * 16 + l15;

  // ---- Phase 2: QKV gemm [64 x 384], all heads at once ----
  floatx4 vacc[4];                          // V part held in regs across bar 2
  {
    #pragma unroll
    for (int p = 0; p < 2; ++p) {           // p=0: Q, p=1: K
      floatx4 acc[4];
      #pragma unroll
      for (int i = 0; i < 4; ++i) acc[i] = ZERO4;
      #pragma unroll
      for (int kt = 0; kt < 4; ++kt) {
        short8v af = *(const short8v*)(&smem[RA + arow * 256 + SWZ16(arow, kt * 64 + l4 * 16)]);
        #pragma unroll
        for (int i = 0; i < 4; ++i) {
          int gcol = (p * 8 + ng * 4 + i) * 16 + l15;
          short8v bf = *(const short8v*)(wqkvT + (size_t)gcol * 128 + kt * 32 + l4 * 8);
          acc[i] = MFMA16(af, bf, acc[i]);
        }
      }
      // scatter to Q (RB) / K (RC), +bias (+scale for Q)
      int rbase = (p == 0) ? RB : RC;
      #pragma unroll
      for (int i = 0; i < 4; ++i) {
        int gcol = (p * 8 + ng * 4 + i) * 16 + l15;
        float bias = bqkv[gcol];
        int c = gcol - p * 128;             // 0..127 channel
        #pragma unroll
        for (int r = 0; r < 4; ++r) {
          int row = mt * 16 + l4 * 4 + r;
          float v = acc[i][r] + bias;
          if (p == 0) v *= SCALE;
          *(short*)(&smem[rbase + row * 256 + SWZ16(row, c * 2)]) = f2bf(v);
        }
      }
    }
    // V part: keep accumulators, store only after bar 2 (VT aliases XS)
    #pragma unroll
    for (int i = 0; i < 4; ++i) vacc[i] = ZERO4;
    #pragma unroll
    for (int kt = 0; kt < 4; ++kt) {
      short8v af = *(const short8v*)(&smem[RA + arow * 256 + SWZ16(arow, kt * 64 + l4 * 16)]);
      #pragma unroll
      for (int i = 0; i < 4; ++i) {
        int gcol = (16 + ng * 4 + i) * 16 + l15;
        short8v bf = *(const short8v*)(wqkvT + (size_t)gcol * 128 + kt * 32 + l4 * 8);
        vacc[i] = MFMA16(af, bf, vacc[i]);
      }
    }
  }
  __syncthreads();   // ---- bar 2 : all XS reads done ----

  // ---- Phase 3a: scatter V^T into RA (row=c, col=kv) ----
  {
    #pragma unroll
    for (int i = 0; i < 4; ++i) {
      int gcol = (16 + ng * 4 + i) * 16 + l15;
      float bias = bqkv[gcol];
      int c = gcol - 256;                   // 0..127
      int kvb = mt * 16 + l4 * 4;
      short4v pv;
      #pragma unroll
      for (int r = 0; r < 4; ++r) pv[r] = f2bf(vacc[i][r] + bias);
      *(short4v*)(&smem[RA + c * 128 + SWZ8(c, kvb * 2)]) = pv;
    }
  }

  // ---- Phase 3b: S = Q K^T in registers + in-register softmax ----
  // wave handles strips s = w and w+8; strip -> head h = s>>2, m-tile s&3.
  floatx4 ps[2][4];                         // normalized P, kept across bar 3
  #pragma unroll
  for (int s2 = 0; s2 < 2; ++s2) {
    int s = w + s2 * 8;
    int h = s >> 2, smt = s & 3;
    int qrow = smt * 16 + l15;
    short8v aq = *(const short8v*)(&smem[RB + qrow * 256 + SWZ16(qrow, h * 64 + l4 * 16)]);
    floatx4 sa[4];
    #pragma unroll
    for (int nt = 0; nt < 4; ++nt) {
      int krow = nt * 16 + l15;
      short8v bk = *(const short8v*)(&smem[RC + krow * 256 + SWZ16(krow, h * 64 + l4 * 16)]);
      sa[nt] = MFMA16(aq, bk, ZERO4);
    }
    // per C-reg r: row = smt*16 + l4*4 + r ; cols spread over (nt, l15)
    #pragma unroll
    for (int r = 0; r < 4; ++r) {
      float m0 = -1e30f;
      #pragma unroll
      for (int nt = 0; nt < 4; ++nt) {
        float sv = ((nt * 16 + l15) < NTOK) ? sa[nt][r] : -1e30f;
        sa[nt][r] = sv;
        m0 = fmaxf(m0, sv);
      }
      #pragma unroll
      for (int off = 1; off < 16; off <<= 1) m0 = fmaxf(m0, __shfl_xor(m0, off, 64));
      float sum = 0.f;
      #pragma unroll
      for (int nt = 0; nt < 4; ++nt) {
        float e = __expf(sa[nt][r] - m0);
        sa[nt][r] = e;
        sum += e;
      }
      #pragma unroll
      for (int off = 1; off < 16; off <<= 1) sum += __shfl_xor(sum, off, 64);
      float rs = __frcp_rn(sum);
      #pragma unroll
      for (int nt = 0; nt < 4; ++nt) ps[s2][nt][r] = sa[nt][r] * rs;
    }
  }
  __syncthreads();   // ---- bar 3 : all Q,K reads done ----

  // ---- Phase 4: scatter P (bf16) into RB/RC ----
  #pragma unroll
  for (int s2 = 0; s2 < 2; ++s2) {
    int s = w + s2 * 8;
    int h = s >> 2, smt = s & 3;
    int pb = RB + h * 8192;                 // h0..h3 contiguous across RB,RC
    #pragma unroll
    for (int nt = 0; nt < 4; ++nt) {
      int col = nt * 16 + l15;
      #pragma unroll
      for (int r = 0; r < 4; ++r) {
        int row = smt * 16 + l4 * 4 + r;
        *(short*)(&smem[pb + row * 128 + SWZ8(row, col * 2)]) = f2bf(ps[s2][nt][r]);
      }
    }
  }
  __syncthreads();   // ---- bar 4 ----

  // ---- Phase 5: O = P V  (reads P in RB/RC, VT in RA) ----
  floatx4 oacc[4];
  {
    #pragma unroll
    for (int i = 0; i < 4; ++i) {
      int nt = ng * 4 + i;                  // output c-tile 0..7
      int h = nt >> 1;
      int pb = RB + h * 8192;
      int prow = mt * 16 + l15;
      int vrow = nt * 16 + l15;             // VT row = channel
      floatx4 a = ZERO4;
      #pragma unroll
      for (int kt = 0; kt < 2; ++kt) {
        short8v ap = *(const short8v*)(&smem[pb + prow * 128 + SWZ8(prow, kt * 64 + l4 * 16)]);
        short8v bv = *(const short8v*)(&smem[RA + vrow * 128 + SWZ8(vrow, kt * 64 + l4 * 16)]);
        a = MFMA16(ap, bv, a);
      }
      oacc[i] = a;
    }
  }
  __syncthreads();   // ---- bar 5 : all VT reads done ----

  // ---- Phase 6: scatter O (bf16) into RA ----
  #pragma unroll
  for (int i = 0; i < 4; ++i) {
    int c = (ng * 4 + i) * 16 + l15;
    #pragma unroll
    for (int r = 0; r < 4; ++r) {
      int row = mt * 16 + l4 * 4 + r;
      *(short*)(&smem[RA + row * 256 + SWZ16(row, c * 2)]) = f2bf(oacc[i][r]);
    }
  }
  __syncthreads();   // ---- bar 6 ----

  // ---- Phase 7: proj [64x128] = O[64x128] * Wp[128x128], write global ----
  {
    floatx4 pacc[4];
    #pragma unroll
    for (int i = 0; i < 4; ++i) pacc[i] = ZERO4;
    #pragma unroll
    for (int kt = 0; kt < 4; ++kt) {
      short8v ao = *(const short8v*)(&smem[RA + arow * 256 + SWZ16(arow, kt * 64 + l4 * 16)]);
      #pragma unroll
      for (int i = 0; i < 4; ++i) {
        int col = (ng * 4 + i) * 16 + l15;
        short8v bp = *(const short8v*)(wprojT + (size_t)col * 128 + kt * 32 + l4 * 8);
        pacc[i] = MFMA16(ao, bp, pacc[i]);
      }
    }
    #pragma unroll
    for (int i = 0; i < 4; ++i) {
      int col = (ng * 4 + i) * 16 + l15;
      float pb2 = bproj[col];
      #pragma unroll
      for (int r = 0; r < 4; ++r) {
        int row = mt * 16 + l4 * 4 + r;
        if (row < NTOK) {
          size_t gi = (((size_t)(base + tok_off<BRANCH>(row))) << 7) + col;
          if constexpr (BRANCH == 0) out[gi] = pacc[i][r] + pb2;
          else out[gi] += pacc[i][r] + pb2;
        }
      }
    }
  }
}

extern "C" void kernel_launch(void* const* d_in, const int* in_sizes, int n_in,
                              void* d_out, int out_size, void* d_ws, size_t ws_size,
                              hipStream_t stream) {
  const float* x         = (const float*)d_in[0];
  const float* qkv_w     = (const float*)d_in[1];
  const float* qkv_b     = (const float*)d_in[2];
  const float* qkv_th_w  = (const float*)d_in[3];
  const float* qkv_th_b  = (const float*)d_in[4];
  const float* qkv_tw_w  = (const float*)d_in[5];
  const float* qkv_tw_b  = (const float*)d_in[6];
  const float* proj_w    = (const float*)d_in[7];
  const float* proj_b    = (const float*)d_in[8];
  const float* proj_th_w = (const float*)d_in[9];
  const float* proj_th_b = (const float*)d_in[10];
  const float* proj_tw_w = (const float*)d_in[11];
  const float* proj_tw_b = (const float*)d_in[12];
  float* out = (float*)d_out;

  const int B = in_sizes[0] / (8 * 56 * 56 * 128);
  short* wsT = (short*)d_ws;

  prep_weights<<<768, 256, 0, stream>>>(qkv_w, qkv_th_w, qkv_tw_w,
                                        proj_w, proj_th_w, proj_tw_w, wsT);

  const short* qT0 = wsT;
  const short* qT1 = wsT + 49152;
  const short* qT2 = wsT + 2 * 49152;
  const short* pT0 = wsT + 3 * 49152;
  const short* pT1 = pT0 + 16384;
  const short* pT2 = pT0 + 2 * 16384;

  // xy writes '=', then ty/tx accumulate (stream-ordered)
  wattn<0, 49><<<B * 512, 512, 0, stream>>>(x, qT0, qkv_b,    pT0, proj_b,    out);
  wattn<1, 56><<<B * 448, 512, 0, stream>>>(x, qT1, qkv_th_b, pT1, proj_th_b, out);
  wattn<2, 56><<<B * 448, 512, 0, stream>>>(x, qT2, qkv_tw_b, pT2, proj_tw_b, out);
}

// Round 5
// 927.174 us; speedup vs baseline: 1.4342x; 1.0632x over previous
//
#include <hip/hip_runtime.h>

// ---------------------------------------------------------------------------
// 3-axis window attention, MI355X gfx950.  Round 5:
//  - single fused dispatch (11264 blocks, branch from blockIdx), out pre-zeroed
//    via hipMemsetAsync, all branches accumulate with atomicAdd (no RMW chain,
//    no inter-dispatch serialization/tails).
//  - S^T softmax: mfma(K,Q) puts each q-row's 64 kv scores in-lane (16) + 4
//    lane-groups -> 15 in-lane ops + 2 shfl hops (was 8 hops/row). P scatter
//    becomes 8 packed ds_write_b64 per wave (was 32 scalar b16).
// Structure: one workgroup per window (49/56 tok padded to 64), 8 waves.
// LDS 48KB aliased: RA = XS -> VT -> O, RB = Q -> P(h0,h1), RC = K -> P(h2,h3).
// ---------------------------------------------------------------------------

typedef __attribute__((ext_vector_type(8))) short short8v;   // 8 x bf16 frag
typedef __attribute__((ext_vector_type(4))) short short4v;
typedef __attribute__((ext_vector_type(4))) float floatx4;

#define MFMA16(a, b, c) __builtin_amdgcn_mfma_f32_16x16x32_bf16((a), (b), (c), 0, 0, 0)

#define SWZ8(row, b)  ((b) ^ (((row) & 7) << 4))
#define SWZ16(row, b) ((b) ^ (((row) & 15) << 4))

__device__ __forceinline__ short f2bf(float f) {  // RNE f32->bf16 bits
  unsigned u = __float_as_uint(f);
  u += 0x7fffu + ((u >> 16) & 1u);
  return (short)(u >> 16);
}

// ---- LDS regions (bytes), total 48 KB -> 3 blocks/CU ----
#define RA 0        // [64][256B] XS  ->  [128][128B] VT  ->  [64][256B] O
#define RB 16384    // [64][256B] Q   ->  P[h0],P[h1]  ([64][128B] each)
#define RC 32768    // [64][256B] K   ->  P[h2],P[h3]
#define LDS_BYTES 49152

__global__ void prep_weights(const float* __restrict__ q0, const float* __restrict__ q1,
                             const float* __restrict__ q2, const float* __restrict__ p0,
                             const float* __restrict__ p1, const float* __restrict__ p2,
                             short* __restrict__ ws) {
  // ws: qkvT[3][384][128] bf16 then projT[3][128][128] bf16 ([out_col][k])
  int idx = blockIdx.x * 256 + threadIdx.x;
  if (idx < 3 * 49152) {
    int b = idx / 49152, r = idx % 49152;
    int n = r >> 7, k = r & 127;
    const float* s = (b == 0) ? q0 : (b == 1) ? q1 : q2;
    ws[idx] = f2bf(s[k * 384 + n]);
  } else if (idx < 3 * 49152 + 3 * 16384) {
    int j = idx - 3 * 49152;
    int b = j / 16384, r = j % 16384;
    int n = r >> 7, k = r & 127;
    const float* s = (b == 0) ? p0 : (b == 1) ? p1 : p2;
    ws[idx] = f2bf(s[k * 128 + n]);
  }
}

__global__ __launch_bounds__(512, 6)
void wattn_all(const float* __restrict__ x, const short* __restrict__ wsT,
               const float* __restrict__ bq0, const float* __restrict__ bq1,
               const float* __restrict__ bq2, const float* __restrict__ bp0,
               const float* __restrict__ bp1, const float* __restrict__ bp2,
               float* __restrict__ out, int nb0, int nb1) {
  __shared__ alignas(256) char smem[LDS_BYTES];
  const int tid = threadIdx.x;
  const int w = tid >> 6;            // wave 0..7
  const int l = tid & 63;
  const int l15 = l & 15;
  const int l4 = l >> 4;             // 0..3
  const float SCALE = 0.17677669529663687f;  // 32^-0.5
  const floatx4 ZERO4 = {0.f, 0.f, 0.f, 0.f};

  // ---- branch resolve (all wave-uniform) ----
  const int bid = blockIdx.x;
  const int br = (bid >= nb0) + (bid >= nb0 + nb1);
  const int lbid = bid - (br == 0 ? 0 : (br == 1 ? nb0 : nb0 + nb1));
  const int NTOK = (br == 0) ? 49 : 56;
  const int S1 = (br == 0) ? 56 : 3136;   // token stride for t/7
  const int S2 = (br == 1) ? 56 : 1;      // token stride for t%7
  int base;
  if (br == 0) {            // xy: (b,d,hb,wb), tok=(ih,iw)
    int b = lbid >> 9, r = lbid & 511;
    int d = r >> 6, hb = (r >> 3) & 7, wb = r & 7;
    base = ((b * 8 + d) * 56 + hb * 7) * 56 + wb * 7;
  } else if (br == 1) {     // ty: (b,hb,wcol), tok=(id,ih)
    int b = lbid / 448, r = lbid % 448;
    int hb = r / 56, wc = r % 56;
    base = (b * 448 + hb * 7) * 56 + wc;
  } else {                  // tx: (b,h,wb), tok=(id,iw)
    int b = lbid / 448, r = lbid % 448;
    int h = r >> 3, wb = r & 7;
    base = (b * 448 + h) * 56 + wb * 7;
  }
  const short* wqkvT  = wsT + br * 49152;
  const short* wprojT = wsT + 3 * 49152 + br * 16384;
  const float* bqkv  = (br == 0) ? bq0 : (br == 1) ? bq1 : bq2;
  const float* bproj = (br == 0) ? bp0 : (br == 1) ? bp1 : bp2;

  // ---- Phase 1: stage x window -> XS (RA), bf16, pad rows zeroed ----
  {
    int rg = tid >> 5;               // 2 rows per wave-instr
    int c4 = (tid & 31) << 2;        // col 0..124 step 4
    #pragma unroll
    for (int it = 0; it < 4; ++it) {
      int t = rg + it * 16;
      short4v v4;
      if (t < NTOK) {
        int q = (unsigned)t / 7u, rm = t - q * 7;
        float4 xv = *(const float4*)(x + (((size_t)(base + q * S1 + rm * S2)) << 7) + c4);
        v4.x = f2bf(xv.x); v4.y = f2bf(xv.y); v4.z = f2bf(xv.z); v4.w = f2bf(xv.w);
      } else {
        v4.x = 0; v4.y = 0; v4.z = 0; v4.w = 0;
      }
      *(short4v*)(&smem[RA + t * 256 + SWZ16(t, c4 * 2)]) = v4;
    }
  }
  __syncthreads();   // ---- bar 1 ----

  const int mt = w & 3, ng = w >> 2;       // wave's m-tile / n-half
  const int arow = mt * 16 + l15;

  // ---- Phase 2: QKV gemm [64 x 384], all heads at once ----
  floatx4 vacc[4];                          // V part held in regs across bar 2
  {
    #pragma unroll
    for (int p = 0; p < 2; ++p) {           // p=0: Q, p=1: K
      floatx4 acc[4];
      #pragma unroll
      for (int i = 0; i < 4; ++i) acc[i] = ZERO4;
      #pragma unroll
      for (int kt = 0; kt < 4; ++kt) {
        short8v af = *(const short8v*)(&smem[RA + arow * 256 + SWZ16(arow, kt * 64 + l4 * 16)]);
        #pragma unroll
        for (int i = 0; i < 4; ++i) {
          int gcol = (p * 8 + ng * 4 + i) * 16 + l15;
          short8v bf = *(const short8v*)(wqkvT + (size_t)gcol * 128 + kt * 32 + l4 * 8);
          acc[i] = MFMA16(af, bf, acc[i]);
        }
      }
      // scatter to Q (RB) / K (RC), +bias (+scale for Q)
      int rbase = (p == 0) ? RB : RC;
      #pragma unroll
      for (int i = 0; i < 4; ++i) {
        int gcol = (p * 8 + ng * 4 + i) * 16 + l15;
        float bias = bqkv[gcol];
        int c = gcol - p * 128;             // 0..127 channel
        #pragma unroll
        for (int r = 0; r < 4; ++r) {
          int row = mt * 16 + l4 * 4 + r;
          float v = acc[i][r] + bias;
          if (p == 0) v *= SCALE;
          *(short*)(&smem[rbase + row * 256 + SWZ16(row, c * 2)]) = f2bf(v);
        }
      }
    }
    // V part: keep accumulators, store only after bar 2 (VT aliases XS)
    #pragma unroll
    for (int i = 0; i < 4; ++i) vacc[i] = ZERO4;
    #pragma unroll
    for (int kt = 0; kt < 4; ++kt) {
      short8v af = *(const short8v*)(&smem[RA + arow * 256 + SWZ16(arow, kt * 64 + l4 * 16)]);
      #pragma unroll
      for (int i = 0; i < 4; ++i) {
        int gcol = (16 + ng * 4 + i) * 16 + l15;
        short8v bf = *(const short8v*)(wqkvT + (size_t)gcol * 128 + kt * 32 + l4 * 8);
        vacc[i] = MFMA16(af, bf, vacc[i]);
      }
    }
  }
  __syncthreads();   // ---- bar 2 : all XS reads done ----

  // ---- Phase 3a: scatter V^T into RA (row=c, col=kv) ----
  {
    #pragma unroll
    for (int i = 0; i < 4; ++i) {
      int gcol = (16 + ng * 4 + i) * 16 + l15;
      float bias = bqkv[gcol];
      int c = gcol - 256;                   // 0..127
      int kvb = mt * 16 + l4 * 4;
      short4v pv;
      #pragma unroll
      for (int r = 0; r < 4; ++r) pv[r] = f2bf(vacc[i][r] + bias);
      *(short4v*)(&smem[RA + c * 128 + SWZ8(c, kvb * 2)]) = pv;
    }
  }

  // ---- Phase 3b: S^T = K Q^T in registers; per-lane softmax over kv ----
  // strip s = w, w+8 -> head h = s>>2, q-tile qt = s&3.  C[kv][q]:
  // kv = kvt*16 + l4*4 + r (in-lane over kvt,r + lane-group l4), q = qt*16+l15.
  floatx4 pT[2][4];                         // normalized P^T, kept across bar 3
  #pragma unroll
  for (int s2 = 0; s2 < 2; ++s2) {
    int s = w + s2 * 8;
    int h = s >> 2, qt = s & 3;
    int qrow = qt * 16 + l15;
    short8v bq = *(const short8v*)(&smem[RB + qrow * 256 + SWZ16(qrow, h * 64 + l4 * 16)]);
    floatx4 st[4];
    #pragma unroll
    for (int kvt = 0; kvt < 4; ++kvt) {
      int krow = kvt * 16 + l15;
      short8v ak = *(const short8v*)(&smem[RC + krow * 256 + SWZ16(krow, h * 64 + l4 * 16)]);
      st[kvt] = MFMA16(ak, bq, ZERO4);      // swapped operands -> S^T tile
    }
    // mask pad kv + in-lane max, 2-hop cross-group max
    float m0 = -1e30f;
    #pragma unroll
    for (int kvt = 0; kvt < 4; ++kvt) {
      #pragma unroll
      for (int r = 0; r < 4; ++r) {
        int kv = kvt * 16 + l4 * 4 + r;
        float sv = (kv < NTOK) ? st[kvt][r] : -1e30f;
        st[kvt][r] = sv;
        m0 = fmaxf(m0, sv);
      }
    }
    m0 = fmaxf(m0, __shfl_xor(m0, 16, 64));
    m0 = fmaxf(m0, __shfl_xor(m0, 32, 64));
    float sum = 0.f;
    #pragma unroll
    for (int kvt = 0; kvt < 4; ++kvt) {
      #pragma unroll
      for (int r = 0; r < 4; ++r) {
        float e = __expf(st[kvt][r] - m0);
        st[kvt][r] = e;
        sum += e;
      }
    }
    sum += __shfl_xor(sum, 16, 64);
    sum += __shfl_xor(sum, 32, 64);
    float rs = __builtin_amdgcn_rcpf(sum);
    #pragma unroll
    for (int kvt = 0; kvt < 4; ++kvt) {
      #pragma unroll
      for (int r = 0; r < 4; ++r) pT[s2][kvt][r] = st[kvt][r] * rs;
    }
  }
  __syncthreads();   // ---- bar 3 : all Q,K reads done ----

  // ---- Phase 4: scatter P^T (bf16) into RB/RC, packed b64 writes ----
  // P stored [64 q][128B kv] per head (same layout PV reads).
  #pragma unroll
  for (int s2 = 0; s2 < 2; ++s2) {
    int s = w + s2 * 8;
    int h = s >> 2, qt = s & 3;
    int pb = RB + h * 8192;
    int qrow = qt * 16 + l15;
    #pragma unroll
    for (int kvt = 0; kvt < 4; ++kvt) {
      short4v pw;
      #pragma unroll
      for (int r = 0; r < 4; ++r) pw[r] = f2bf(pT[s2][kvt][r]);
      *(short4v*)(&smem[pb + qrow * 128 + SWZ8(qrow, kvt * 32 + l4 * 8)]) = pw;
    }
  }
  __syncthreads();   // ---- bar 4 ----

  // ---- Phase 5: O = P V  (reads P in RB/RC, VT in RA) ----
  floatx4 oacc[4];
  {
    #pragma unroll
    for (int i = 0; i < 4; ++i) {
      int nt = ng * 4 + i;                  // output c-tile 0..7
      int h = nt >> 1;
      int pb = RB + h * 8192;
      int prow = mt * 16 + l15;
      int vrow = nt * 16 + l15;             // VT row = channel
      floatx4 a = ZERO4;
      #pragma unroll
      for (int kt = 0; kt < 2; ++kt) {
        short8v ap = *(const short8v*)(&smem[pb + prow * 128 + SWZ8(prow, kt * 64 + l4 * 16)]);
        short8v bv = *(const short8v*)(&smem[RA + vrow * 128 + SWZ8(vrow, kt * 64 + l4 * 16)]);
        a = MFMA16(ap, bv, a);
      }
      oacc[i] = a;
    }
  }
  __syncthreads();   // ---- bar 5 : all VT reads done ----

  // ---- Phase 6: scatter O (bf16) into RA ----
  #pragma unroll
  for (int i = 0; i < 4; ++i) {
    int c = (ng * 4 + i) * 16 + l15;
    #pragma unroll
    for (int r = 0; r < 4; ++r) {
      int row = mt * 16 + l4 * 4 + r;
      *(short*)(&smem[RA + row * 256 + SWZ16(row, c * 2)]) = f2bf(oacc[i][r]);
    }
  }
  __syncthreads();   // ---- bar 6 ----

  // ---- Phase 7: proj [64x128] = O[64x128] * Wp[128x128], atomicAdd out ----
  {
    floatx4 pacc[4];
    #pragma unroll
    for (int i = 0; i < 4; ++i) pacc[i] = ZERO4;
    #pragma unroll
    for (int kt = 0; kt < 4; ++kt) {
      short8v ao = *(const short8v*)(&smem[RA + arow * 256 + SWZ16(arow, kt * 64 + l4 * 16)]);
      #pragma unroll
      for (int i = 0; i < 4; ++i) {
        int col = (ng * 4 + i) * 16 + l15;
        short8v bp = *(const short8v*)(wprojT + (size_t)col * 128 + kt * 32 + l4 * 8);
        pacc[i] = MFMA16(ao, bp, pacc[i]);
      }
    }
    #pragma unroll
    for (int i = 0; i < 4; ++i) {
      int col = (ng * 4 + i) * 16 + l15;
      float pb2 = bproj[col];
      #pragma unroll
      for (int r = 0; r < 4; ++r) {
        int row = mt * 16 + l4 * 4 + r;
        if (row < NTOK) {
          int q = (unsigned)row / 7u, rm = row - q * 7;
          size_t gi = (((size_t)(base + q * S1 + rm * S2)) << 7) + col;
          atomicAdd(&out[gi], pacc[i][r] + pb2);
        }
      }
    }
  }
}

extern "C" void kernel_launch(void* const* d_in, const int* in_sizes, int n_in,
                              void* d_out, int out_size, void* d_ws, size_t ws_size,
                              hipStream_t stream) {
  const float* x         = (const float*)d_in[0];
  const float* qkv_w     = (const float*)d_in[1];
  const float* qkv_b     = (const float*)d_in[2];
  const float* qkv_th_w  = (const float*)d_in[3];
  const float* qkv_th_b  = (const float*)d_in[4];
  const float* qkv_tw_w  = (const float*)d_in[5];
  const float* qkv_tw_b  = (const float*)d_in[6];
  const float* proj_w    = (const float*)d_in[7];
  const float* proj_b    = (const float*)d_in[8];
  const float* proj_th_w = (const float*)d_in[9];
  const float* proj_th_b = (const float*)d_in[10];
  const float* proj_tw_w = (const float*)d_in[11];
  const float* proj_tw_b = (const float*)d_in[12];
  float* out = (float*)d_out;

  const int B = in_sizes[0] / (8 * 56 * 56 * 128);
  short* wsT = (short*)d_ws;

  // out = 0, then every branch accumulates atomically (order-free)
  hipMemsetAsync(d_out, 0, (size_t)out_size * sizeof(float), stream);
  prep_weights<<<768, 256, 0, stream>>>(qkv_w, qkv_th_w, qkv_tw_w,
                                        proj_w, proj_th_w, proj_tw_w, wsT);

  const int nb0 = B * 512, nb1 = B * 448;
  wattn_all<<<nb0 + 2 * nb1, 512, 0, stream>>>(
      x, wsT, qkv_b, qkv_th_b, qkv_tw_b, proj_b, proj_th_b, proj_tw_b,
      out, nb0, nb1);
}